// Round 7
// baseline (1768.901 us; speedup 1.0000x reference)
//
#include <hip/hip_runtime.h>

typedef __attribute__((ext_vector_type(8))) short short8;
typedef __attribute__((ext_vector_type(4))) float float4v;
typedef unsigned short u16;

#define Sdim 256
#define Udim 128
#define Hdim 512
#define MT   32       // rows per block
#define XS   392      // xh stride (u16): 384+8
#define XLS  264      // xl stride (state cols only): 256+8
#define HS   520      // h stride: 512+8
#define NW   589824   // total weight elements
#define W1_OFF 0
#define W2_OFF 196608
#define W3_OFF 458752
#define NSTEPS 21     // np-ref float32 h: floor(1/0.05f)=20 scaled + 1 unscaled

__device__ __forceinline__ float bf2f(u16 u) {
    union { unsigned int i; float f; } x; x.i = ((unsigned int)u) << 16; return x.f;
}
__device__ __forceinline__ u16 f2bf(float f) {
    union { float f; unsigned int i; } x; x.f = f;
    unsigned int r = x.i + 0x7FFFu + ((x.i >> 16) & 1u);  // RNE
    return (u16)(r >> 16);
}

__global__ void probe_dtype(const u16* __restrict__ w1, int* __restrict__ flag) {
    __shared__ int cnt;
    if (threadIdx.x == 0) cnt = 0;
    __syncthreads();
    u16 u = w1[threadIdx.x];
    int e = (u >> 7) & 0xFF;
    int pass = (u == 0) || (e >= 0x60 && e <= 0x8F);
    if (pass) atomicAdd(&cnt, 1);
    __syncthreads();
    if (threadIdx.x == 0) *flag = (cnt >= 240) ? 1 : 0;   // 1 = bf16 inputs
}

// pack W (row-major KxN) into MFMA B-frag tiles, hi+lo bf16 planes.
__global__ void pack_weights(const void* __restrict__ Wraw, u16* __restrict__ hi,
                             u16* __restrict__ lo, int K, int N, const int* __restrict__ flagp) {
    int f = blockIdx.x * 256 + threadIdx.x;
    int KT = K >> 5;
    int total = (N >> 4) * KT * 64;
    if (f >= total) return;
    int bf = *flagp;
    int lane = f & 63, tile = f >> 6;
    int kt = tile % KT, nt = tile / KT;
    int k0 = kt * 32 + ((lane >> 4) << 3);
    int n  = nt * 16 + (lane & 15);
    short8 vh, vl;
#pragma unroll
    for (int j = 0; j < 8; ++j) {
        float wv = bf ? bf2f(((const u16*)Wraw)[(size_t)(k0 + j) * N + n])
                      : ((const float*)Wraw)[(size_t)(k0 + j) * N + n];
        u16 h = f2bf(wv);
        vh[j] = (short)h;
        vl[j] = (short)f2bf(wv - bf2f(h));
    }
    *reinterpret_cast<short8*>(hi + (size_t)f * 8) = vh;
    *reinterpret_cast<short8*>(lo + (size_t)f * 8) = vl;
}

#define MFMA __builtin_amdgcn_mfma_f32_16x16x32_bf16

// Pipelined layer GEMM: explicit register double-buffer over kt.
// A hi (2 msubs) [+ A lo for kt<KTL] @ B hi [+ B lo if WLO]; B tile idx = t*KT+kt.
template<int KT, int KTL, int NT, bool WLO>
__device__ __forceinline__ void mmP(const u16* ah, const u16* al, const int as, const int als,
                                    const u16* __restrict__ wh, const u16* __restrict__ wl,
                                    float4v acc[2][NT]) {
    short8 Bh[2][NT], Bl[2][NT];
    short8 A0[2], A1[2], A0l[2], A1l[2];
#pragma unroll
    for (int t = 0; t < NT; ++t) {
        Bh[0][t] = *(const short8*)(wh + (size_t)(t * KT) * 512);
        if (WLO) Bl[0][t] = *(const short8*)(wl + (size_t)(t * KT) * 512);
    }
    A0[0] = *(const short8*)(ah);
    A1[0] = *(const short8*)(ah + 16 * as);
    if (KTL > 0) {
        A0l[0] = *(const short8*)(al);
        A1l[0] = *(const short8*)(al + 16 * als);
    }
#pragma unroll
    for (int kt = 0; kt < KT; ++kt) {
        const int cur = kt & 1, nxt = cur ^ 1;
        if (kt + 1 < KT) {   // prefetch kt+1 while computing kt
#pragma unroll
            for (int t = 0; t < NT; ++t) {
                Bh[nxt][t] = *(const short8*)(wh + (size_t)(t * KT + kt + 1) * 512);
                if (WLO) Bl[nxt][t] = *(const short8*)(wl + (size_t)(t * KT + kt + 1) * 512);
            }
            A0[nxt] = *(const short8*)(ah + (kt + 1) * 32);
            A1[nxt] = *(const short8*)(ah + 16 * as + (kt + 1) * 32);
            if (kt + 1 < KTL) {
                A0l[nxt] = *(const short8*)(al + (kt + 1) * 32);
                A1l[nxt] = *(const short8*)(al + 16 * als + (kt + 1) * 32);
            }
        }
#pragma unroll
        for (int t = 0; t < NT; ++t) {
            acc[0][t] = MFMA(A0[cur], Bh[cur][t], acc[0][t], 0, 0, 0);
            acc[1][t] = MFMA(A1[cur], Bh[cur][t], acc[1][t], 0, 0, 0);
            if (WLO) {
                acc[0][t] = MFMA(A0[cur], Bl[cur][t], acc[0][t], 0, 0, 0);
                acc[1][t] = MFMA(A1[cur], Bl[cur][t], acc[1][t], 0, 0, 0);
            }
            if (kt < KTL) {   // x-lo correction reuses Bh (no extra load)
                acc[0][t] = MFMA(A0l[cur], Bh[cur][t], acc[0][t], 0, 0, 0);
                acc[1][t] = MFMA(A1l[cur], Bh[cur][t], acc[1][t], 0, 0, 0);
            }
        }
    }
}

template<bool BF>
__device__ __forceinline__ void body(
    const void* state_raw, const void* user_raw,
    const void* b1r, const void* b2r, const void* b3r,
    const u16* __restrict__ wh_all, const u16* __restrict__ wl_all, void* outp,
    u16* xh, u16* xl, u16* H1, u16* H2) {

    const int tid = threadIdx.x, w = tid >> 6, lane = tid & 63;   // 16 waves
    const int col16 = lane & 15, quad = lane >> 4;
    const int r0 = blockIdx.x * MT;

    // ---- one-time: user params -> xh cols 256..383 (hi only) ----
    if (tid < 512) {
        int row = tid >> 4;
        int c8 = (tid & 15) * 8;
        if (BF) {
            short8 v = *(const short8*)((const u16*)user_raw + (size_t)(r0 + row) * Udim + c8);
            *(short8*)(xh + row * XS + Sdim + c8) = v;
        } else {
            const float* up = (const float*)user_raw + (size_t)(r0 + row) * Udim + c8;
            short8 v;
#pragma unroll
            for (int j = 0; j < 8; ++j) v[j] = (short)f2bf(up[j]);
            *(short8*)(xh + row * XS + Sdim + c8) = v;
        }
    }
    // ---- biases (C-layout: depend on col only) ----
    float b1f[2], b2f[2], b3f;
#pragma unroll
    for (int t = 0; t < 2; ++t) {
        int i = w * 32 + t * 16 + col16;
        b1f[t] = BF ? bf2f(((const u16*)b1r)[i]) : ((const float*)b1r)[i];
        b2f[t] = BF ? bf2f(((const u16*)b2r)[i]) : ((const float*)b2r)[i];
    }
    {
        int i = w * 16 + col16;
        b3f = BF ? bf2f(((const u16*)b3r)[i]) : ((const float*)b3r)[i];
    }
    // ---- state: fp32 regs (C-layout, wave owns 16 cols) + hi/lo split ----
    float st[2][4];
#pragma unroll
    for (int m = 0; m < 2; ++m)
#pragma unroll
        for (int r = 0; r < 4; ++r) {
            int row = m * 16 + quad * 4 + r;
            int col = w * 16 + col16;
            float v = BF ? bf2f(((const u16*)state_raw)[(size_t)(r0 + row) * Sdim + col])
                         : ((const float*)state_raw)[(size_t)(r0 + row) * Sdim + col];
            st[m][r] = v;
            u16 h = f2bf(v);
            xh[row * XS + col] = h;
            xl[row * XLS + col] = f2bf(v - bf2f(h));
        }
    __syncthreads();

    const u16* w1h = wh_all + W1_OFF + (size_t)(w * 2) * 12 * 512 + lane * 8;
    const u16* w1l = wl_all + W1_OFF + (size_t)(w * 2) * 12 * 512 + lane * 8;
    const u16* w2h = wh_all + W2_OFF + (size_t)(w * 2) * 16 * 512 + lane * 8;
    const u16* w3h = wh_all + W3_OFF + (size_t)(w)     * 16 * 512 + lane * 8;

    const u16* aXh = xh + col16 * XS + quad * 8;
    const u16* aXl = xl + col16 * XLS + quad * 8;
    const u16* aH1 = H1 + col16 * HS + quad * 8;
    const u16* aH2 = H2 + col16 * HS + quad * 8;

    for (int step = 0; step < NSTEPS; ++step) {
        const float dt = (step == NSTEPS - 1) ? 1.0f : 0.05f;

        // ---- L1: silu(x @ W1 + b1) -> H1. W1 hi+lo; x-lo over state cols (kt<8). ----
        {
            float4v acc[2][2];
#pragma unroll
            for (int m = 0; m < 2; ++m)
#pragma unroll
                for (int t = 0; t < 2; ++t) acc[m][t] = (float4v){b1f[t], b1f[t], b1f[t], b1f[t]};
            if (BF) mmP<12, 0, 2, false>(aXh, aXl, XS, XLS, w1h, w1l, acc);
            else    mmP<12, 8, 2, true >(aXh, aXl, XS, XLS, w1h, w1l, acc);
#pragma unroll
            for (int m = 0; m < 2; ++m)
#pragma unroll
                for (int t = 0; t < 2; ++t)
#pragma unroll
                    for (int r = 0; r < 4; ++r) {
                        float v = acc[m][t][r];
                        float s = v / (1.0f + __expf(-v));
                        H1[(m * 16 + quad * 4 + r) * HS + w * 32 + t * 16 + col16] = f2bf(s);
                    }
        }
        __syncthreads();   // (a) h1 visible

        // ---- L2: silu(h1 @ W2 + b2) -> H2 (W2 hi only) ----
        {
            float4v acc[2][2];
#pragma unroll
            for (int m = 0; m < 2; ++m)
#pragma unroll
                for (int t = 0; t < 2; ++t) acc[m][t] = (float4v){b2f[t], b2f[t], b2f[t], b2f[t]};
            mmP<16, 0, 2, false>(aH1, aH1, HS, HS, w2h, w2h, acc);
#pragma unroll
            for (int m = 0; m < 2; ++m)
#pragma unroll
                for (int t = 0; t < 2; ++t)
#pragma unroll
                    for (int r = 0; r < 4; ++r) {
                        float v = acc[m][t][r];
                        float s = v / (1.0f + __expf(-v));
                        H2[(m * 16 + quad * 4 + r) * HS + w * 32 + t * 16 + col16] = f2bf(s);
                    }
        }
        __syncthreads();   // (b) h2 visible; fences this step's H1 reads

        // ---- L3: h2 @ W3 + b3 -> st += f*dt (W3 hi only); split-write state ----
        {
            float4v acc[2][1];
#pragma unroll
            for (int m = 0; m < 2; ++m) acc[m][0] = (float4v){b3f, b3f, b3f, b3f};
            mmP<16, 0, 1, false>(aH2, aH2, HS, HS, w3h, w3h, acc);
#pragma unroll
            for (int m = 0; m < 2; ++m)
#pragma unroll
                for (int r = 0; r < 4; ++r) {
                    float v = st[m][r] + acc[m][0][r] * dt;
                    st[m][r] = v;
                    int row = m * 16 + quad * 4 + r;
                    int col = w * 16 + col16;
                    u16 h = f2bf(v);
                    xh[row * XS + col] = h;     // x not read since L1: safe
                    xl[row * XLS + col] = f2bf(v - bf2f(h));
                }
        }
        __syncthreads();   // (c) x(state) ready; fences this step's H2 reads
    }

    // ---- final state -> out ----
#pragma unroll
    for (int m = 0; m < 2; ++m)
#pragma unroll
        for (int r = 0; r < 4; ++r) {
            int row = m * 16 + quad * 4 + r;
            int col = w * 16 + col16;
            if (BF) ((u16*)outp)[(size_t)(r0 + row) * Sdim + col] = f2bf(st[m][r]);
            else    ((float*)outp)[(size_t)(r0 + row) * Sdim + col] = st[m][r];
        }
}

__global__ __launch_bounds__(1024, 4) void fused_ode(
    const void* state_raw, const void* user_raw,
    const void* b1r, const void* b2r, const void* b3r,
    const u16* __restrict__ wh, const u16* __restrict__ wl,
    const int* __restrict__ flagp, void* outp) {

    __shared__ __align__(16) u16 xh[MT * XS];   // 25,088 B
    __shared__ __align__(16) u16 xl[MT * XLS];  // 16,896 B
    __shared__ __align__(16) u16 H1[MT * HS];   // 33,280 B
    __shared__ __align__(16) u16 H2[MT * HS];   // 33,280 B  -> 108,544 B

    if (*flagp)
        body<true >(state_raw, user_raw, b1r, b2r, b3r, wh, wl, outp, xh, xl, H1, H2);
    else
        body<false>(state_raw, user_raw, b1r, b2r, b3r, wh, wl, outp, xh, xl, H1, H2);
}

extern "C" void kernel_launch(void* const* d_in, const int* in_sizes, int n_in,
                              void* d_out, int out_size, void* d_ws, size_t ws_size,
                              hipStream_t stream) {
    u16* wh = (u16*)d_ws;
    u16* wl = wh + NW;
    int* flagp = (int*)((char*)d_ws + (size_t)2 * NW * sizeof(u16));

    probe_dtype<<<1, 256, 0, stream>>>((const u16*)d_in[2], flagp);
    pack_weights<<< 96, 256, 0, stream>>>(d_in[2], wh + W1_OFF, wl + W1_OFF, 384, 512, flagp);
    pack_weights<<<128, 256, 0, stream>>>(d_in[4], wh + W2_OFF, wl + W2_OFF, 512, 512, flagp);
    pack_weights<<< 64, 256, 0, stream>>>(d_in[6], wh + W3_OFF, wl + W3_OFF, 512, 256, flagp);

    fused_ode<<<8192 / MT, 1024, 0, stream>>>(d_in[0], d_in[1], d_in[3], d_in[5], d_in[7],
                                              wh, wl, flagp, d_out);
}

// Round 8
// 481.565 us; speedup vs baseline: 3.6732x; 3.6732x over previous
//
#include <hip/hip_runtime.h>

typedef __attribute__((ext_vector_type(8))) short short8;
typedef __attribute__((ext_vector_type(4))) float float4v;
typedef unsigned short u16;

#define Sdim 256
#define Udim 128
#define Hdim 512
#define MT   32       // rows per block
#define XS   392      // xh stride (u16): 384+8
#define XLS  264      // xl stride (state cols only): 256+8
#define HS   520      // h stride: 512+8
#define NW   589824   // total weight elements
#define W1_OFF 0
#define W2_OFF 196608
#define W3_OFF 458752
#define NSTEPS 21     // np-ref float32 h: floor(1/0.05f)=20 scaled + 1 unscaled

__device__ __forceinline__ float bf2f(u16 u) {
    union { unsigned int i; float f; } x; x.i = ((unsigned int)u) << 16; return x.f;
}
__device__ __forceinline__ u16 f2bf(float f) {
    union { float f; unsigned int i; } x; x.f = f;
    unsigned int r = x.i + 0x7FFFu + ((x.i >> 16) & 1u);  // RNE
    return (u16)(r >> 16);
}

__global__ void probe_dtype(const u16* __restrict__ w1, int* __restrict__ flag) {
    __shared__ int cnt;
    if (threadIdx.x == 0) cnt = 0;
    __syncthreads();
    u16 u = w1[threadIdx.x];
    int e = (u >> 7) & 0xFF;
    int pass = (u == 0) || (e >= 0x60 && e <= 0x8F);
    if (pass) atomicAdd(&cnt, 1);
    __syncthreads();
    if (threadIdx.x == 0) *flag = (cnt >= 240) ? 1 : 0;   // 1 = bf16 inputs
}

// pack W (row-major KxN) into MFMA B-frag tiles, hi+lo bf16 planes.
__global__ void pack_weights(const void* __restrict__ Wraw, u16* __restrict__ hi,
                             u16* __restrict__ lo, int K, int N, const int* __restrict__ flagp) {
    int f = blockIdx.x * 256 + threadIdx.x;
    int KT = K >> 5;
    int total = (N >> 4) * KT * 64;
    if (f >= total) return;
    int bf = *flagp;
    int lane = f & 63, tile = f >> 6;
    int kt = tile % KT, nt = tile / KT;
    int k0 = kt * 32 + ((lane >> 4) << 3);
    int n  = nt * 16 + (lane & 15);
    short8 vh, vl;
#pragma unroll
    for (int j = 0; j < 8; ++j) {
        float wv = bf ? bf2f(((const u16*)Wraw)[(size_t)(k0 + j) * N + n])
                      : ((const float*)Wraw)[(size_t)(k0 + j) * N + n];
        u16 h = f2bf(wv);
        vh[j] = (short)h;
        vl[j] = (short)f2bf(wv - bf2f(h));
    }
    *reinterpret_cast<short8*>(hi + (size_t)f * 8) = vh;
    *reinterpret_cast<short8*>(lo + (size_t)f * 8) = vl;
}

#define MFMA __builtin_amdgcn_mfma_f32_16x16x32_bf16

// Compiler-scheduled layer GEMM (R6 style — no explicit pipelining; R7's
// manual double-buffer was lowered to scratch: WRITE_SIZE 8->385 MB).
// A hi (2 msubs) [+ A lo for kt<KTL, reusing Bh] @ B hi [+ B lo if WLO].
// B tile idx = t*KTB + kt.
template<int KT, int KTB, int KTL, int NT, bool WLO>
__device__ __forceinline__ void mm1(const u16* ah, const u16* al, const int as, const int als,
                                    const u16* __restrict__ wh, const u16* __restrict__ wl,
                                    float4v acc[2][NT]) {
#pragma unroll 2
    for (int kt = 0; kt < KT; ++kt) {
        short8 A0 = *(const short8*)(ah + kt * 32);
        short8 A1 = *(const short8*)(ah + 16 * as + kt * 32);
        short8 A0l, A1l;
        if (kt < KTL) {
            A0l = *(const short8*)(al + kt * 32);
            A1l = *(const short8*)(al + 16 * als + kt * 32);
        }
#pragma unroll
        for (int t = 0; t < NT; ++t) {
            short8 Bh = *(const short8*)(wh + (size_t)(t * KTB + kt) * 512);
            acc[0][t] = MFMA(A0, Bh, acc[0][t], 0, 0, 0);
            acc[1][t] = MFMA(A1, Bh, acc[1][t], 0, 0, 0);
            if (WLO) {
                short8 Bl = *(const short8*)(wl + (size_t)(t * KTB + kt) * 512);
                acc[0][t] = MFMA(A0, Bl, acc[0][t], 0, 0, 0);
                acc[1][t] = MFMA(A1, Bl, acc[1][t], 0, 0, 0);
            }
            if (kt < KTL) {     // x-lo correction reuses Bh — no extra load
                acc[0][t] = MFMA(A0l, Bh, acc[0][t], 0, 0, 0);
                acc[1][t] = MFMA(A1l, Bh, acc[1][t], 0, 0, 0);
            }
        }
    }
}

template<bool BF>
__device__ __forceinline__ void body(
    const void* state_raw, const void* user_raw,
    const void* b1r, const void* b2r, const void* b3r,
    const u16* __restrict__ wh_all, const u16* __restrict__ wl_all, void* outp,
    u16* xh, u16* xl, u16* H1, u16* H2) {

    const int tid = threadIdx.x, w = tid >> 6, lane = tid & 63;   // 16 waves
    const int col16 = lane & 15, quad = lane >> 4;
    const int r0 = blockIdx.x * MT;

    // ---- one-time: user params -> xh cols 256..383 (hi only) ----
    if (tid < 512) {
        int row = tid >> 4;
        int c8 = (tid & 15) * 8;
        if (BF) {
            short8 v = *(const short8*)((const u16*)user_raw + (size_t)(r0 + row) * Udim + c8);
            *(short8*)(xh + row * XS + Sdim + c8) = v;
        } else {
            const float* up = (const float*)user_raw + (size_t)(r0 + row) * Udim + c8;
            short8 v;
#pragma unroll
            for (int j = 0; j < 8; ++j) v[j] = (short)f2bf(up[j]);
            *(short8*)(xh + row * XS + Sdim + c8) = v;
        }
    }
    // ---- biases (C-layout: depend on col only) ----
    float b1f[2], b2f[2], b3f;
#pragma unroll
    for (int t = 0; t < 2; ++t) {
        int i = w * 32 + t * 16 + col16;
        b1f[t] = BF ? bf2f(((const u16*)b1r)[i]) : ((const float*)b1r)[i];
        b2f[t] = BF ? bf2f(((const u16*)b2r)[i]) : ((const float*)b2r)[i];
    }
    {
        int i = w * 16 + col16;
        b3f = BF ? bf2f(((const u16*)b3r)[i]) : ((const float*)b3r)[i];
    }
    // ---- state: fp32 regs (C-layout, wave owns 16 cols) + hi/lo split ----
    float st[2][4];
#pragma unroll
    for (int m = 0; m < 2; ++m)
#pragma unroll
        for (int r = 0; r < 4; ++r) {
            int row = m * 16 + quad * 4 + r;
            int col = w * 16 + col16;
            float v = BF ? bf2f(((const u16*)state_raw)[(size_t)(r0 + row) * Sdim + col])
                         : ((const float*)state_raw)[(size_t)(r0 + row) * Sdim + col];
            st[m][r] = v;
            u16 h = f2bf(v);
            xh[row * XS + col] = h;
            xl[row * XLS + col] = f2bf(v - bf2f(h));
        }
    __syncthreads();

    const u16* w1h = wh_all + W1_OFF + (size_t)(w * 2) * 12 * 512 + lane * 8;
    const u16* w1l = wl_all + W1_OFF + (size_t)(w * 2) * 12 * 512 + lane * 8;
    const u16* w2h = wh_all + W2_OFF + (size_t)(w * 2) * 16 * 512 + lane * 8;
    const u16* w3h = wh_all + W3_OFF + (size_t)(w)     * 16 * 512 + lane * 8;

    const u16* aXh = xh + col16 * XS + quad * 8;
    const u16* aXl = xl + col16 * XLS + quad * 8;
    const u16* aH1 = H1 + col16 * HS + quad * 8;
    const u16* aH2 = H2 + col16 * HS + quad * 8;

    for (int step = 0; step < NSTEPS; ++step) {
        const float dt = (step == NSTEPS - 1) ? 1.0f : 0.05f;

        // ---- L1: silu(x @ W1 + b1) -> H1. W1 hi+lo; x-lo fused (kt<8). ----
        {
            float4v acc[2][2];
#pragma unroll
            for (int m = 0; m < 2; ++m)
#pragma unroll
                for (int t = 0; t < 2; ++t) acc[m][t] = (float4v){b1f[t], b1f[t], b1f[t], b1f[t]};
            if (BF) mm1<12, 12, 0, 2, false>(aXh, aXl, XS, XLS, w1h, w1l, acc);
            else    mm1<12, 12, 8, 2, true >(aXh, aXl, XS, XLS, w1h, w1l, acc);
#pragma unroll
            for (int m = 0; m < 2; ++m)
#pragma unroll
                for (int t = 0; t < 2; ++t)
#pragma unroll
                    for (int r = 0; r < 4; ++r) {
                        float v = acc[m][t][r];
                        float s = v / (1.0f + __expf(-v));
                        H1[(m * 16 + quad * 4 + r) * HS + w * 32 + t * 16 + col16] = f2bf(s);
                    }
        }
        __syncthreads();   // (a) h1 visible

        // ---- L2: silu(h1 @ W2 + b2) -> H2 (W2 hi only) ----
        {
            float4v acc[2][2];
#pragma unroll
            for (int m = 0; m < 2; ++m)
#pragma unroll
                for (int t = 0; t < 2; ++t) acc[m][t] = (float4v){b2f[t], b2f[t], b2f[t], b2f[t]};
            mm1<16, 16, 0, 2, false>(aH1, aH1, HS, HS, w2h, w2h, acc);
#pragma unroll
            for (int m = 0; m < 2; ++m)
#pragma unroll
                for (int t = 0; t < 2; ++t)
#pragma unroll
                    for (int r = 0; r < 4; ++r) {
                        float v = acc[m][t][r];
                        float s = v / (1.0f + __expf(-v));
                        H2[(m * 16 + quad * 4 + r) * HS + w * 32 + t * 16 + col16] = f2bf(s);
                    }
        }
        __syncthreads();   // (b) h2 visible; fences this step's H1 reads

        // ---- L3: h2 @ W3 + b3 -> st += f*dt (W3 hi only); split-write state ----
        {
            float4v acc[2][1];
#pragma unroll
            for (int m = 0; m < 2; ++m) acc[m][0] = (float4v){b3f, b3f, b3f, b3f};
            mm1<16, 16, 0, 1, false>(aH2, aH2, HS, HS, w3h, w3h, acc);
#pragma unroll
            for (int m = 0; m < 2; ++m)
#pragma unroll
                for (int r = 0; r < 4; ++r) {
                    float v = st[m][r] + acc[m][0][r] * dt;
                    st[m][r] = v;
                    int row = m * 16 + quad * 4 + r;
                    int col = w * 16 + col16;
                    u16 h = f2bf(v);
                    xh[row * XS + col] = h;     // x not read since L1: safe
                    xl[row * XLS + col] = f2bf(v - bf2f(h));
                }
        }
        __syncthreads();   // (c) x(state) ready; fences this step's H2 reads
    }

    // ---- final state -> out ----
#pragma unroll
    for (int m = 0; m < 2; ++m)
#pragma unroll
        for (int r = 0; r < 4; ++r) {
            int row = m * 16 + quad * 4 + r;
            int col = w * 16 + col16;
            if (BF) ((u16*)outp)[(size_t)(r0 + row) * Sdim + col] = f2bf(st[m][r]);
            else    ((float*)outp)[(size_t)(r0 + row) * Sdim + col] = st[m][r];
        }
}

__global__ __launch_bounds__(1024, 4) void fused_ode(
    const void* state_raw, const void* user_raw,
    const void* b1r, const void* b2r, const void* b3r,
    const u16* __restrict__ wh, const u16* __restrict__ wl,
    const int* __restrict__ flagp, void* outp) {

    __shared__ __align__(16) u16 xh[MT * XS];   // 25,088 B
    __shared__ __align__(16) u16 xl[MT * XLS];  // 16,896 B
    __shared__ __align__(16) u16 H1[MT * HS];   // 33,280 B
    __shared__ __align__(16) u16 H2[MT * HS];   // 33,280 B  -> 108,544 B

    if (*flagp)
        body<true >(state_raw, user_raw, b1r, b2r, b3r, wh, wl, outp, xh, xl, H1, H2);
    else
        body<false>(state_raw, user_raw, b1r, b2r, b3r, wh, wl, outp, xh, xl, H1, H2);
}

extern "C" void kernel_launch(void* const* d_in, const int* in_sizes, int n_in,
                              void* d_out, int out_size, void* d_ws, size_t ws_size,
                              hipStream_t stream) {
    u16* wh = (u16*)d_ws;
    u16* wl = wh + NW;
    int* flagp = (int*)((char*)d_ws + (size_t)2 * NW * sizeof(u16));

    probe_dtype<<<1, 256, 0, stream>>>((const u16*)d_in[2], flagp);
    pack_weights<<< 96, 256, 0, stream>>>(d_in[2], wh + W1_OFF, wl + W1_OFF, 384, 512, flagp);
    pack_weights<<<128, 256, 0, stream>>>(d_in[4], wh + W2_OFF, wl + W2_OFF, 512, 512, flagp);
    pack_weights<<< 64, 256, 0, stream>>>(d_in[6], wh + W3_OFF, wl + W3_OFF, 512, 256, flagp);

    fused_ode<<<8192 / MT, 1024, 0, stream>>>(d_in[0], d_in[1], d_in[3], d_in[5], d_in[7],
                                              wh, wl, flagp, d_out);
}